// Round 2
// baseline (790.990 us; speedup 1.0000x reference)
//
#include <hip/hip_runtime.h>
#include <hip/hip_cooperative_groups.h>

namespace cg = cooperative_groups;

#define NS_MAX 2048
#define ES_MAX 16384
#define LN_EPS 1e-5f

struct GnnParams {
  const float* x; const int* src; const int* dst; const int* curp;
  const float* W1; const float* b1; const float* g1; const float* be1;
  const float* W2; const float* b2; const float* g2; const float* be2;
  const float* W3; const float* b3; const float* g3; const float* be3;
  int* mask; float* deg; int* lidx; int* nodelist;
  float* dis; float* wself; int* esrc; int* edst; int* cnt;
  float* H; float* AGG; float* H3; float* AGG3; float* X3;
  float* out;
  int N; int E;
};

__global__ __launch_bounds__(256, 4) void fused_gnn(GnnParams p){
  cg::grid_group grid = cg::this_grid();
  const int tid = threadIdx.x;
  const int gt  = blockIdx.x*256 + tid;
  const int gs  = gridDim.x*256;
  const int cur = p.curp[0];
  const int sub = tid >> 7;      // node slot within block (0/1)
  const int d   = tid & 127;     // feature dim within slot

  __shared__ float row[2][128];
  __shared__ float redm[2][2];
  __shared__ float redv[2][2];
  __shared__ float redp[4][64];

  // cross-wave (128-thread sub-group) sum
  auto subsum128 = [&](float s, float (*red)[2]) -> float {
    #pragma unroll
    for (int o = 32; o >= 1; o >>= 1) s += __shfl_xor(s, o);
    if ((tid & 63) == 0) red[sub][(tid >> 6) & 1] = s;
    __syncthreads();
    return red[sub][0] + red[sub][1];
  };
  auto ln128 = [&](float v, float gd, float bed) -> float {
    float tot = subsum128(v, redm);
    float mu  = tot * (1.0f/128.0f);
    float dv  = v - mu;
    float tot2 = subsum128(dv*dv, redv);
    float var = tot2 * (1.0f/128.0f);
    return dv * rsqrtf(var + LN_EPS) * gd + bed;
  };

  // ---------------- P0: init ----------------
  for (int i = gt; i < p.N; i += gs){ p.mask[i] = (i == cur) ? 1 : 0; p.deg[i] = 0.0f; }
  if (gt == 0){ p.cnt[0] = 0; p.cnt[1] = 0; }
  grid.sync();

  // ---------------- P1: BFS hop 1 (dst == cur -> mark src 0->2) ------------
  if ((p.E & 3) == 0){
    const int4* d4 = (const int4*)p.dst;
    int nv = p.E >> 2;
    for (int v = gt; v < nv; v += gs){
      int4 dd = d4[v]; int b = v << 2;
      if (dd.x == cur) atomicCAS(&p.mask[p.src[b+0]], 0, 2);
      if (dd.y == cur) atomicCAS(&p.mask[p.src[b+1]], 0, 2);
      if (dd.z == cur) atomicCAS(&p.mask[p.src[b+2]], 0, 2);
      if (dd.w == cur) atomicCAS(&p.mask[p.src[b+3]], 0, 2);
    }
  } else {
    for (int e = gt; e < p.E; e += gs)
      if (p.dst[e] == cur) atomicCAS(&p.mask[p.src[e]], 0, 2);
  }
  grid.sync();

  // ---------------- P2: BFS hop 2 (mask[dst] in {1,2} -> mark src 0->3) ----
  if ((p.E & 3) == 0){
    const int4* d4 = (const int4*)p.dst;
    int nv = p.E >> 2;
    for (int v = gt; v < nv; v += gs){
      int4 dd = d4[v]; int b = v << 2;
      int m0 = p.mask[dd.x], m1 = p.mask[dd.y], m2 = p.mask[dd.z], m3 = p.mask[dd.w];
      if (m0 == 1 || m0 == 2) atomicCAS(&p.mask[p.src[b+0]], 0, 3);
      if (m1 == 1 || m1 == 2) atomicCAS(&p.mask[p.src[b+1]], 0, 3);
      if (m2 == 1 || m2 == 2) atomicCAS(&p.mask[p.src[b+2]], 0, 3);
      if (m3 == 1 || m3 == 2) atomicCAS(&p.mask[p.src[b+3]], 0, 3);
    }
  } else {
    for (int e = gt; e < p.E; e += gs){
      int m = p.mask[p.dst[e]];
      if (m == 1 || m == 2) atomicCAS(&p.mask[p.src[e]], 0, 3);
    }
  }
  grid.sync();

  // ---------------- P3: deg + edge compact + node compact ------------------
  {
    auto edge_one = [&](int eidx, int dvert){
      if (p.mask[dvert]){
        int s = p.src[eidx];
        if (p.mask[s]){
          atomicAdd(&p.deg[dvert], 1.0f);
          int idx = atomicAdd(&p.cnt[1], 1);
          if (idx < ES_MAX){ p.esrc[idx] = s; p.edst[idx] = dvert; }
        }
      }
    };
    if ((p.E & 3) == 0){
      const int4* d4 = (const int4*)p.dst;
      int nv = p.E >> 2;
      for (int v = gt; v < nv; v += gs){
        int4 dd = d4[v]; int b = v << 2;
        edge_one(b+0, dd.x); edge_one(b+1, dd.y);
        edge_one(b+2, dd.z); edge_one(b+3, dd.w);
      }
    } else {
      for (int e = gt; e < p.E; e += gs) edge_one(e, p.dst[e]);
    }
    for (int v = gt; v < p.N; v += gs){
      if (p.mask[v]){
        int l = atomicAdd(&p.cnt[0], 1);
        if (l < NS_MAX){ p.nodelist[l] = v; p.lidx[v] = l; }
      }
    }
  }
  grid.sync();

  const int ncnt = min(p.cnt[0], NS_MAX);
  const int ec   = min(p.cnt[1], ES_MAX);

  // ---------------- P4: gather + dis/wself + gemm1 -------------------------
  for (int base = blockIdx.x*2; base < ncnt; base += gridDim.x*2){
    int l = base + sub; bool act = (l < ncnt);
    float xv = 0.0f, wsl = 0.0f;
    if (act){
      int v = p.nodelist[l];
      xv = p.x[(size_t)v*128 + d];
      float dv = p.deg[v] + 1.0f;
      wsl = 1.0f / dv;
      if (d == 0){ p.dis[l] = rsqrtf(dv); p.wself[l] = wsl; }
    }
    row[sub][d] = xv;
    __syncthreads();
    float acc = 0.0f;
    #pragma unroll 8
    for (int k = 0; k < 128; ++k) acc = fmaf(row[sub][k], p.W1[k*128 + d], acc);
    if (act){ p.H[l*128 + d] = acc; p.AGG[l*128 + d] = acc * wsl; }
    __syncthreads();
  }
  grid.sync();

  // ---------------- P5: scatter layer 1 ------------------------------------
  for (int i = blockIdx.x*2 + sub; i < ec; i += gridDim.x*2){
    int ls = p.lidx[p.esrc[i]];
    int ld = p.lidx[p.edst[i]];
    float w = p.dis[ls] * p.dis[ld];
    atomicAdd(&p.AGG[ld*128 + d], w * p.H[ls*128 + d]);
  }
  grid.sync();

  // ---------------- P6: ln1 + gemm2 ----------------------------------------
  for (int base = blockIdx.x*2; base < ncnt; base += gridDim.x*2){
    int l = base + sub; bool act = (l < ncnt);
    float v = act ? (p.AGG[l*128 + d] + p.b1[d]) : 0.0f;
    v = fmaxf(v, 0.0f);
    float y = ln128(v, p.g1[d], p.be1[d]);
    row[sub][d] = y;
    __syncthreads();
    float acc = 0.0f;
    #pragma unroll 8
    for (int k = 0; k < 128; ++k) acc = fmaf(row[sub][k], p.W2[k*128 + d], acc);
    if (act){ float wsl = p.wself[l]; p.H[l*128 + d] = acc; p.AGG[l*128 + d] = acc * wsl; }
    __syncthreads();
  }
  grid.sync();

  // ---------------- P7: scatter layer 2 ------------------------------------
  for (int i = blockIdx.x*2 + sub; i < ec; i += gridDim.x*2){
    int ls = p.lidx[p.esrc[i]];
    int ld = p.lidx[p.edst[i]];
    float w = p.dis[ls] * p.dis[ld];
    atomicAdd(&p.AGG[ld*128 + d], w * p.H[ls*128 + d]);
  }
  grid.sync();

  // ---------------- P8: ln2 + gemm3 (128 -> 64) ----------------------------
  for (int base = blockIdx.x*2; base < ncnt; base += gridDim.x*2){
    int l = base + sub; bool act = (l < ncnt);
    float v = act ? (p.AGG[l*128 + d] + p.b2[d]) : 0.0f;
    v = fmaxf(v, 0.0f);
    float y = ln128(v, p.g2[d], p.be2[d]);
    row[sub][d] = y;
    __syncthreads();
    if (d < 64){
      float acc = 0.0f;
      #pragma unroll 8
      for (int k = 0; k < 128; ++k) acc = fmaf(row[sub][k], p.W3[k*64 + d], acc);
      if (act){ float wsl = p.wself[l]; p.H3[l*64 + d] = acc; p.AGG3[l*64 + d] = acc * wsl; }
    }
    __syncthreads();
  }
  grid.sync();

  // ---------------- P9: scatter layer 3 (dim 64) ---------------------------
  if (d < 64){
    for (int i = blockIdx.x*2 + sub; i < ec; i += gridDim.x*2){
      int ls = p.lidx[p.esrc[i]];
      int ld = p.lidx[p.edst[i]];
      float w = p.dis[ls] * p.dis[ld];
      atomicAdd(&p.AGG3[ld*64 + d], w * p.H3[ls*64 + d]);
    }
  }
  grid.sync();

  // ---------------- P10: ln3 (64-dim, single wave per sub) -----------------
  for (int base = blockIdx.x*2; base < ncnt; base += gridDim.x*2){
    int l = base + sub; bool act = (l < ncnt) && (d < 64);
    float v = act ? (p.AGG3[l*64 + d] + p.b3[d]) : 0.0f;
    v = fmaxf(v, 0.0f);
    float s = v;
    #pragma unroll
    for (int o = 32; o >= 1; o >>= 1) s += __shfl_xor(s, o);
    float mu = s * (1.0f/64.0f);
    float dv = v - mu;
    float s2 = dv*dv;
    #pragma unroll
    for (int o = 32; o >= 1; o >>= 1) s2 += __shfl_xor(s2, o);
    float var = s2 * (1.0f/64.0f);
    float y = dv * rsqrtf(var + LN_EPS) * p.g3[d] + p.be3[d];
    if (act) p.X3[l*64 + d] = y;
  }
  grid.sync();

  // ---------------- P11: mean pool (block 0) -------------------------------
  if (blockIdx.x == 0){
    int grp = tid >> 6, t = tid & 63;   // 4 groups x 64 lanes
    float s = 0.0f;
    for (int l = grp; l < ncnt; l += 4) s += p.X3[l*64 + t];
    redp[grp][t] = s;
    __syncthreads();
    if (grp == 0){
      float tot = redp[0][t] + redp[1][t] + redp[2][t] + redp[3][t];
      p.out[t] = tot / (float)ncnt;
    }
  }
}

extern "C" void kernel_launch(void* const* d_in, const int* in_sizes, int n_in,
                              void* d_out, int out_size, void* d_ws, size_t ws_size,
                              hipStream_t stream) {
  const float* x    = (const float*)d_in[0];
  const int*   ei   = (const int*)d_in[1];
  const int*   curp = (const int*)d_in[2];

  int N = in_sizes[0] / 128;
  int E = in_sizes[1] / 2;

  char* wp = (char*)d_ws;
  auto carve = [&](size_t bytes) -> void* {
    void* r = (void*)wp;
    wp += (bytes + 255) & ~(size_t)255;
    return r;
  };
  GnnParams p;
  p.x = x; p.src = ei; p.dst = ei + E; p.curp = curp;
  p.W1 = (const float*)d_in[3];  p.b1 = (const float*)d_in[4];
  p.g1 = (const float*)d_in[5];  p.be1= (const float*)d_in[6];
  p.W2 = (const float*)d_in[7];  p.b2 = (const float*)d_in[8];
  p.g2 = (const float*)d_in[9];  p.be2= (const float*)d_in[10];
  p.W3 = (const float*)d_in[11]; p.b3 = (const float*)d_in[12];
  p.g3 = (const float*)d_in[13]; p.be3= (const float*)d_in[14];
  p.mask     = (int*)  carve((size_t)N*4);
  p.deg      = (float*)carve((size_t)N*4);
  p.lidx     = (int*)  carve((size_t)N*4);
  p.nodelist = (int*)  carve(NS_MAX*4);
  p.dis      = (float*)carve(NS_MAX*4);
  p.wself    = (float*)carve(NS_MAX*4);
  p.esrc     = (int*)  carve(ES_MAX*4);
  p.edst     = (int*)  carve(ES_MAX*4);
  p.cnt      = (int*)  carve(64);
  p.H        = (float*)carve((size_t)NS_MAX*128*4);
  p.AGG      = (float*)carve((size_t)NS_MAX*128*4);
  p.H3       = (float*)carve((size_t)NS_MAX*64*4);
  p.AGG3     = (float*)carve((size_t)NS_MAX*64*4);
  p.X3       = (float*)carve((size_t)NS_MAX*64*4);
  p.out      = (float*)d_out;
  p.N = N; p.E = E;
  (void)ws_size; (void)n_in; (void)out_size;

  void* args[] = { &p };
  hipLaunchCooperativeKernel((void*)fused_gnn, dim3(512), dim3(256), args, 0, stream);
}

// Round 3
// 307.390 us; speedup vs baseline: 2.5732x; 2.5732x over previous
//
#include <hip/hip_runtime.h>

#define NS_MAX 2048
#define ES_MAX 16384
#define LN_EPS 1e-5f
#define NBLK 128
#define NTHR 256

// bar word layout (ints, 64B-separated lines): [0]=arrive, [16]=gen, [32]=done,
// [48]=node count, [49]=edge count. All zeroed by host memset.
struct GnnParams {
  const float* x; const int* src; const int* dst; const int* curp;
  const float* W1; const float* b1; const float* g1; const float* be1;
  const float* W2; const float* b2; const float* g2; const float* be2;
  const float* W3; const float* b3; const float* g3; const float* be3;
  int* bar;        // zeroed
  int* mask;       // [N] zeroed
  int* deg;        // [NS_MAX] zeroed (local-indexed in-degree)
  float* AGG;      // [NS_MAX*128] zeroed
  float* AGG3;     // [NS_MAX*64] zeroed
  int* nodelist; int* lidx; int* esrc; int* edst; int* els; int* eld;
  float* H; float* H3; float* X3;
  float* out;
  int N; int E;
};

__device__ __forceinline__ void gbar(int* bar){
  __syncthreads();
  if (threadIdx.x == 0){
    int g = __hip_atomic_load(&bar[16], __ATOMIC_RELAXED, __HIP_MEMORY_SCOPE_AGENT);
    int a = __hip_atomic_fetch_add(&bar[0], 1, __ATOMIC_ACQ_REL, __HIP_MEMORY_SCOPE_AGENT);
    if (a == NBLK-1){
      __hip_atomic_store(&bar[0], 0, __ATOMIC_RELAXED, __HIP_MEMORY_SCOPE_AGENT);
      __hip_atomic_fetch_add(&bar[16], 1, __ATOMIC_RELEASE, __HIP_MEMORY_SCOPE_AGENT);
    } else {
      while (__hip_atomic_load(&bar[16], __ATOMIC_RELAXED, __HIP_MEMORY_SCOPE_AGENT) == g)
        __builtin_amdgcn_s_sleep(2);
      __builtin_amdgcn_fence(__ATOMIC_ACQUIRE, "agent");
    }
  }
  __syncthreads();
}

__global__ __launch_bounds__(NTHR) void fused_gnn(GnnParams p){
  const int tid = threadIdx.x;
  const int gt  = blockIdx.x*NTHR + tid;
  const int gs  = NBLK*NTHR;
  const int sub = tid >> 7;      // 128-thread slot (0/1)
  const int d   = tid & 127;
  const int s4  = tid >> 6;      // 64-thread slot (0..3)
  const int t64 = tid & 63;
  const int cur = p.curp[0];

  __shared__ float row[2][128];
  __shared__ float redm[2][2];
  __shared__ float redv[2][2];
  __shared__ float redp[4][64];
  __shared__ int lastflag;

  auto subsum128 = [&](float s, float (*red)[2]) -> float {
    #pragma unroll
    for (int o = 32; o >= 1; o >>= 1) s += __shfl_xor(s, o);
    if ((tid & 63) == 0) red[sub][(tid >> 6) & 1] = s;
    __syncthreads();
    return red[sub][0] + red[sub][1];
  };
  auto ln128 = [&](float v, float gd, float bed) -> float {
    float tot = subsum128(v, redm);
    float mu  = tot * (1.0f/128.0f);
    float dv  = v - mu;
    float tot2 = subsum128(dv*dv, redv);
    float var = tot2 * (1.0f/128.0f);
    return dv * rsqrtf(var + LN_EPS) * gd + bed;
  };

  const int nv = p.E >> 2;
  const int4* d4 = (const int4*)p.dst;

  // ---------- P1: hop 1 (dst == cur -> mark src 0->2) + seed cur ----------
  if (gt == 0) __hip_atomic_store(&p.mask[cur], 1, __ATOMIC_RELAXED, __HIP_MEMORY_SCOPE_AGENT);
  for (int v = gt; v < nv; v += gs){
    int4 dd = d4[v]; int b = v << 2;
    if (dd.x == cur) atomicCAS(&p.mask[p.src[b+0]], 0, 2);
    if (dd.y == cur) atomicCAS(&p.mask[p.src[b+1]], 0, 2);
    if (dd.z == cur) atomicCAS(&p.mask[p.src[b+2]], 0, 2);
    if (dd.w == cur) atomicCAS(&p.mask[p.src[b+3]], 0, 2);
  }
  for (int e = (nv<<2) + gt; e < p.E; e += gs)
    if (p.dst[e] == cur) atomicCAS(&p.mask[p.src[e]], 0, 2);
  gbar(p.bar);

  // ---------- P2: hop 2 (mask[dst] in {1,2} -> mark src 0->3) -------------
  for (int v = gt; v < nv; v += gs){
    int4 dd = d4[v]; int b = v << 2;
    int m0 = p.mask[dd.x], m1 = p.mask[dd.y], m2 = p.mask[dd.z], m3 = p.mask[dd.w];
    if (m0 == 1 || m0 == 2) atomicCAS(&p.mask[p.src[b+0]], 0, 3);
    if (m1 == 1 || m1 == 2) atomicCAS(&p.mask[p.src[b+1]], 0, 3);
    if (m2 == 1 || m2 == 2) atomicCAS(&p.mask[p.src[b+2]], 0, 3);
    if (m3 == 1 || m3 == 2) atomicCAS(&p.mask[p.src[b+3]], 0, 3);
  }
  for (int e = (nv<<2) + gt; e < p.E; e += gs){
    int m = p.mask[p.dst[e]];
    if (m == 1 || m == 2) atomicCAS(&p.mask[p.src[e]], 0, 3);
  }
  gbar(p.bar);

  // ---------- P3: edge compact (global ids) + node compact ----------------
  {
    auto edge_one = [&](int eidx, int dvert){
      if (p.mask[dvert]){
        int s = p.src[eidx];
        if (p.mask[s]){
          int idx = atomicAdd(&p.bar[49], 1);
          if (idx < ES_MAX){ p.esrc[idx] = s; p.edst[idx] = dvert; }
        }
      }
    };
    for (int v = gt; v < nv; v += gs){
      int4 dd = d4[v]; int b = v << 2;
      edge_one(b+0, dd.x); edge_one(b+1, dd.y);
      edge_one(b+2, dd.z); edge_one(b+3, dd.w);
    }
    for (int e = (nv<<2) + gt; e < p.E; e += gs) edge_one(e, p.dst[e]);
    for (int v = gt; v < p.N; v += gs){
      if (p.mask[v]){
        int l = atomicAdd(&p.bar[48], 1);
        if (l < NS_MAX){ p.nodelist[l] = v; p.lidx[v] = l; }
      }
    }
  }
  gbar(p.bar);

  const int ncnt = min(__hip_atomic_load(&p.bar[48], __ATOMIC_RELAXED, __HIP_MEMORY_SCOPE_AGENT), NS_MAX);
  const int ec   = min(__hip_atomic_load(&p.bar[49], __ATOMIC_RELAXED, __HIP_MEMORY_SCOPE_AGENT), ES_MAX);

  // ---------- P4: localize edges + deg count + gather + gemm1 -------------
  for (int i = gt; i < ec; i += gs){
    int ls = p.lidx[p.esrc[i]], ld = p.lidx[p.edst[i]];
    p.els[i] = ls; p.eld[i] = ld;
    atomicAdd(&p.deg[ld], 1);
  }
  for (int base = blockIdx.x*2; base < ncnt; base += NBLK*2){
    int l = base + sub; bool act = (l < ncnt);
    float xv = 0.0f;
    if (act){ int v = p.nodelist[l]; xv = p.x[(size_t)v*128 + d]; }
    row[sub][d] = xv;
    __syncthreads();
    float acc = 0.0f;
    #pragma unroll 8
    for (int k = 0; k < 128; ++k) acc = fmaf(row[sub][k], p.W1[k*128 + d], acc);
    if (act) p.H[l*128 + d] = acc;
    __syncthreads();
  }
  gbar(p.bar);

  // ---------- P5: scatter layer 1 -----------------------------------------
  for (int i = blockIdx.x*2 + sub; i < ec; i += NBLK*2){
    int ls = p.els[i], ld = p.eld[i];
    float w = rsqrtf((float)(p.deg[ls]+1)) * rsqrtf((float)(p.deg[ld]+1));
    atomicAdd(&p.AGG[ld*128 + d], w * p.H[ls*128 + d]);
  }
  gbar(p.bar);

  // ---------- P6: ln1 (+self term) + gemm2, re-zero AGG slot --------------
  for (int base = blockIdx.x*2; base < ncnt; base += NBLK*2){
    int l = base + sub; bool act = (l < ncnt);
    float v = 0.0f;
    if (act){
      float wself = 1.0f / (float)(p.deg[l] + 1);
      v = p.AGG[l*128 + d] + p.H[l*128 + d]*wself + p.b1[d];
    }
    v = fmaxf(v, 0.0f);
    float y = ln128(v, p.g1[d], p.be1[d]);
    row[sub][d] = y;
    __syncthreads();
    float acc = 0.0f;
    #pragma unroll 8
    for (int k = 0; k < 128; ++k) acc = fmaf(row[sub][k], p.W2[k*128 + d], acc);
    if (act){ p.H[l*128 + d] = acc; p.AGG[l*128 + d] = 0.0f; }
    __syncthreads();
  }
  gbar(p.bar);

  // ---------- P7: scatter layer 2 -----------------------------------------
  for (int i = blockIdx.x*2 + sub; i < ec; i += NBLK*2){
    int ls = p.els[i], ld = p.eld[i];
    float w = rsqrtf((float)(p.deg[ls]+1)) * rsqrtf((float)(p.deg[ld]+1));
    atomicAdd(&p.AGG[ld*128 + d], w * p.H[ls*128 + d]);
  }
  gbar(p.bar);

  // ---------- P8: ln2 + gemm3 (128 -> 64) ---------------------------------
  for (int base = blockIdx.x*2; base < ncnt; base += NBLK*2){
    int l = base + sub; bool act = (l < ncnt);
    float v = 0.0f;
    if (act){
      float wself = 1.0f / (float)(p.deg[l] + 1);
      v = p.AGG[l*128 + d] + p.H[l*128 + d]*wself + p.b2[d];
    }
    v = fmaxf(v, 0.0f);
    float y = ln128(v, p.g2[d], p.be2[d]);
    row[sub][d] = y;
    __syncthreads();
    if (d < 64){
      float acc = 0.0f;
      #pragma unroll 8
      for (int k = 0; k < 128; ++k) acc = fmaf(row[sub][k], p.W3[k*64 + d], acc);
      if (act) p.H3[l*64 + d] = acc;
    }
    __syncthreads();
  }
  gbar(p.bar);

  // ---------- P9: scatter layer 3 (dim 64) --------------------------------
  for (int i = blockIdx.x*4 + s4; i < ec; i += NBLK*4){
    int ls = p.els[i], ld = p.eld[i];
    float w = rsqrtf((float)(p.deg[ls]+1)) * rsqrtf((float)(p.deg[ld]+1));
    atomicAdd(&p.AGG3[ld*64 + t64], w * p.H3[ls*64 + t64]);
  }
  gbar(p.bar);

  // ---------- P10: ln3 -> X3, then last-block pools ------------------------
  for (int base = blockIdx.x*4; base < ncnt; base += NBLK*4){
    int l = base + s4; bool act = (l < ncnt);
    float v = 0.0f;
    if (act){
      float wself = 1.0f / (float)(p.deg[l] + 1);
      v = p.AGG3[l*64 + t64] + p.H3[l*64 + t64]*wself + p.b3[t64];
    }
    v = fmaxf(v, 0.0f);
    float s = v;
    #pragma unroll
    for (int o = 32; o >= 1; o >>= 1) s += __shfl_xor(s, o);
    float mu = s * (1.0f/64.0f);
    float dv = v - mu;
    float s2 = dv*dv;
    #pragma unroll
    for (int o = 32; o >= 1; o >>= 1) s2 += __shfl_xor(s2, o);
    float var = s2 * (1.0f/64.0f);
    float y = dv * rsqrtf(var + LN_EPS) * p.g3[t64] + p.be3[t64];
    if (act) p.X3[l*64 + t64] = y;
  }
  __syncthreads();
  if (tid == 0){
    int t0 = __hip_atomic_fetch_add(&p.bar[32], 1, __ATOMIC_ACQ_REL, __HIP_MEMORY_SCOPE_AGENT);
    lastflag = (t0 == NBLK-1) ? 1 : 0;
  }
  __syncthreads();
  if (lastflag){
    float s = 0.0f;
    for (int l = s4; l < ncnt; l += 4) s += p.X3[l*64 + t64];
    redp[s4][t64] = s;
    __syncthreads();
    if (s4 == 0){
      float tot = redp[0][t64] + redp[1][t64] + redp[2][t64] + redp[3][t64];
      p.out[t64] = tot / (float)ncnt;
    }
  }
}

extern "C" void kernel_launch(void* const* d_in, const int* in_sizes, int n_in,
                              void* d_out, int out_size, void* d_ws, size_t ws_size,
                              hipStream_t stream) {
  const float* x    = (const float*)d_in[0];
  const int*   ei   = (const int*)d_in[1];
  const int*   curp = (const int*)d_in[2];

  int N = in_sizes[0] / 128;
  int E = in_sizes[1] / 2;

  char* wp = (char*)d_ws;
  auto carve = [&](size_t bytes) -> void* {
    void* r = (void*)wp;
    wp += (bytes + 255) & ~(size_t)255;
    return r;
  };
  GnnParams p;
  p.x = x; p.src = ei; p.dst = ei + E; p.curp = curp;
  p.W1 = (const float*)d_in[3];  p.b1 = (const float*)d_in[4];
  p.g1 = (const float*)d_in[5];  p.be1= (const float*)d_in[6];
  p.W2 = (const float*)d_in[7];  p.b2 = (const float*)d_in[8];
  p.g2 = (const float*)d_in[9];  p.be2= (const float*)d_in[10];
  p.W3 = (const float*)d_in[11]; p.b3 = (const float*)d_in[12];
  p.g3 = (const float*)d_in[13]; p.be3= (const float*)d_in[14];

  // ---- zeroed head (single memset) ----
  p.bar      = (int*)  carve(256);
  p.mask     = (int*)  carve((size_t)N*4);
  p.deg      = (int*)  carve(NS_MAX*4);
  p.AGG      = (float*)carve((size_t)NS_MAX*128*4);
  p.AGG3     = (float*)carve((size_t)NS_MAX*64*4);
  size_t head_bytes = (size_t)(wp - (char*)d_ws);
  // ---- uninitialized tail ----
  p.nodelist = (int*)  carve(NS_MAX*4);
  p.lidx     = (int*)  carve((size_t)N*4);
  p.esrc     = (int*)  carve(ES_MAX*4);
  p.edst     = (int*)  carve(ES_MAX*4);
  p.els      = (int*)  carve(ES_MAX*4);
  p.eld      = (int*)  carve(ES_MAX*4);
  p.H        = (float*)carve((size_t)NS_MAX*128*4);
  p.H3       = (float*)carve((size_t)NS_MAX*64*4);
  p.X3       = (float*)carve((size_t)NS_MAX*64*4);
  p.out      = (float*)d_out;
  p.N = N; p.E = E;
  (void)ws_size; (void)n_in; (void)out_size;

  hipMemsetAsync(d_ws, 0, head_bytes, stream);
  void* args[] = { &p };
  hipLaunchCooperativeKernel((void*)fused_gnn, dim3(NBLK), dim3(NTHR), args, 0, stream);
}

// Round 8
// 249.445 us; speedup vs baseline: 3.1710x; 1.2323x over previous
//
#include <hip/hip_runtime.h>

#define NS_MAX 2048
#define ES_MAX 16384
#define LN_EPS 1e-5f
#define NBLK 128
#define NTHR 256
#define BMP_MAX 3328   // words -> supports N <= 106496 in LDS

// bar words (64B apart): [0]=arrive, [16]=gen, [32]=done-ticket, [48]=node cnt, [49]=edge cnt
struct GnnParams {
  const float* x; const int* src; const int* dst; const int* curp;
  const float* W1; const float* b1; const float* g1; const float* be1;
  const float* W2; const float* b2; const float* g2; const float* be2;
  const float* W3; const float* b3; const float* g3; const float* be3;
  int* bar; unsigned* B1; unsigned* B2; int* deg;      // zeroed by host memset
  int* nodelist; int* lidx; int* esrc; int* edst; int* els; int* eld;
  float* H; float* AGG; float* H3; float* AGG3; float* X3;
  float* out;
  int N; int E;
};

__device__ __forceinline__ void gbar(int* bar){
  __syncthreads();
  if (threadIdx.x == 0){
    int g = __hip_atomic_load(&bar[16], __ATOMIC_RELAXED, __HIP_MEMORY_SCOPE_AGENT);
    int a = __hip_atomic_fetch_add(&bar[0], 1, __ATOMIC_ACQ_REL, __HIP_MEMORY_SCOPE_AGENT);
    if (a == NBLK-1){
      __hip_atomic_store(&bar[0], 0, __ATOMIC_RELAXED, __HIP_MEMORY_SCOPE_AGENT);
      __hip_atomic_fetch_add(&bar[16], 1, __ATOMIC_ACQ_REL, __HIP_MEMORY_SCOPE_AGENT);
    } else {
      while (__hip_atomic_load(&bar[16], __ATOMIC_RELAXED, __HIP_MEMORY_SCOPE_AGENT) == g)
        __builtin_amdgcn_s_sleep(2);
      __builtin_amdgcn_fence(__ATOMIC_ACQUIRE, "agent");
    }
  }
  __syncthreads();
}

__global__ __launch_bounds__(NTHR) void fused_gnn(GnnParams p){
  const int tid = threadIdx.x;
  const int gt  = blockIdx.x*NTHR + tid;
  const int gs  = NBLK*NTHR;
  const int sub = tid >> 7;      // 128-thread slot (0/1)
  const int d   = tid & 127;
  const int s4  = tid >> 6;      // 64-thread slot (0..3)
  const int t64 = tid & 63;
  const int cur = p.curp[0];
  const int NW  = (p.N + 31) >> 5;
  const bool fits = (NW <= BMP_MAX);

  __shared__ unsigned bmp[BMP_MAX];
  __shared__ float row[2][128];
  __shared__ float redm[2][2];
  __shared__ float redv[2][2];
  __shared__ float redp[4][64];
  __shared__ int lastflag;

  auto subsum128 = [&](float s, float (*red)[2]) -> float {
    #pragma unroll
    for (int o = 32; o >= 1; o >>= 1) s += __shfl_xor(s, o);
    if ((tid & 63) == 0) red[sub][(tid >> 6) & 1] = s;
    __syncthreads();
    return red[sub][0] + red[sub][1];
  };
  auto ln128 = [&](float v, float gd, float bed) -> float {
    float tot = subsum128(v, redm);
    float mu  = tot * (1.0f/128.0f);
    float dv  = v - mu;
    float tot2 = subsum128(dv*dv, redv);
    float var = tot2 * (1.0f/128.0f);
    return dv * rsqrtf(var + LN_EPS) * gd + bed;
  };

  const int nv = p.E >> 2;
  const int4* d4 = (const int4*)p.dst;

  // ================= P1: hop 1 (dst == cur -> B1 |= src), seed cur ========
  if (gt == 0) atomicOr(&p.B1[cur >> 5], 1u << (cur & 31));
  {
    auto proc = [&](int4 dd, int b){
      if (dd.x == cur){ int s = p.src[b+0]; atomicOr(&p.B1[s>>5], 1u<<(s&31)); }
      if (dd.y == cur){ int s = p.src[b+1]; atomicOr(&p.B1[s>>5], 1u<<(s&31)); }
      if (dd.z == cur){ int s = p.src[b+2]; atomicOr(&p.B1[s>>5], 1u<<(s&31)); }
      if (dd.w == cur){ int s = p.src[b+3]; atomicOr(&p.B1[s>>5], 1u<<(s&31)); }
    };
    for (int v0 = gt; v0 < nv; v0 += 4*gs){
      int v1 = v0+gs, v2 = v0+2*gs, v3 = v0+3*gs;
      bool c1 = v1 < nv, c2 = v2 < nv, c3 = v3 < nv;
      int4 a0 = d4[v0], a1, a2, a3;
      if (c1) a1 = d4[v1];
      if (c2) a2 = d4[v2];
      if (c3) a3 = d4[v3];
      proc(a0, v0<<2);
      if (c1) proc(a1, v1<<2);
      if (c2) proc(a2, v2<<2);
      if (c3) proc(a3, v3<<2);
    }
    for (int e = (nv<<2) + gt; e < p.E; e += gs)
      if (p.dst[e] == cur){ int s = p.src[e]; atomicOr(&p.B1[s>>5], 1u<<(s&31)); }
  }
  gbar(p.bar);

  // ================= P2: hop 2 (B1[dst] -> B2 |= src) =====================
  {
    if (fits){
      for (int w = tid; w < NW; w += NTHR) bmp[w] = p.B1[w];
    }
    __syncthreads();
    auto test1 = [&](int v)->bool{
      return fits ? ((bmp[v>>5] >> (v&31)) & 1u)
                  : ((p.B1[v>>5] >> (v&31)) & 1u);
    };
    auto proc = [&](int4 dd, int b){
      if (test1(dd.x)){ int s = p.src[b+0]; atomicOr(&p.B2[s>>5], 1u<<(s&31)); }
      if (test1(dd.y)){ int s = p.src[b+1]; atomicOr(&p.B2[s>>5], 1u<<(s&31)); }
      if (test1(dd.z)){ int s = p.src[b+2]; atomicOr(&p.B2[s>>5], 1u<<(s&31)); }
      if (test1(dd.w)){ int s = p.src[b+3]; atomicOr(&p.B2[s>>5], 1u<<(s&31)); }
    };
    for (int v0 = gt; v0 < nv; v0 += 4*gs){
      int v1 = v0+gs, v2 = v0+2*gs, v3 = v0+3*gs;
      bool c1 = v1 < nv, c2 = v2 < nv, c3 = v3 < nv;
      int4 a0 = d4[v0], a1, a2, a3;
      if (c1) a1 = d4[v1];
      if (c2) a2 = d4[v2];
      if (c3) a3 = d4[v3];
      proc(a0, v0<<2);
      if (c1) proc(a1, v1<<2);
      if (c2) proc(a2, v2<<2);
      if (c3) proc(a3, v3<<2);
    }
    for (int e = (nv<<2) + gt; e < p.E; e += gs){
      int dd = p.dst[e];
      if (test1(dd)){ int s = p.src[e]; atomicOr(&p.B2[s>>5], 1u<<(s&31)); }
    }
  }
  gbar(p.bar);

  // ================= P3: F = B1|B2: edge compact + node compact ===========
  {
    __syncthreads();  // bmp reuse
    if (fits){
      for (int w = tid; w < NW; w += NTHR) bmp[w] = p.B1[w] | p.B2[w];
    }
    __syncthreads();
    auto testF = [&](int v)->bool{
      return fits ? ((bmp[v>>5] >> (v&31)) & 1u)
                  : (((p.B1[v>>5] | p.B2[v>>5]) >> (v&31)) & 1u);
    };
    auto proc = [&](int dd, int b){
      if (testF(dd)){
        int s = p.src[b];
        if (testF(s)){
          int idx = atomicAdd(&p.bar[49], 1);
          if (idx < ES_MAX){ p.esrc[idx] = s; p.edst[idx] = dd; }
        }
      }
    };
    for (int v0 = gt; v0 < nv; v0 += 4*gs){
      int v1 = v0+gs, v2 = v0+2*gs, v3 = v0+3*gs;
      bool c1 = v1 < nv, c2 = v2 < nv, c3 = v3 < nv;
      int4 a0 = d4[v0], a1, a2, a3;
      if (c1) a1 = d4[v1];
      if (c2) a2 = d4[v2];
      if (c3) a3 = d4[v3];
      proc(a0.x, (v0<<2)+0); proc(a0.y, (v0<<2)+1); proc(a0.z, (v0<<2)+2); proc(a0.w, (v0<<2)+3);
      if (c1){ proc(a1.x, (v1<<2)+0); proc(a1.y, (v1<<2)+1); proc(a1.z, (v1<<2)+2); proc(a1.w, (v1<<2)+3); }
      if (c2){ proc(a2.x, (v2<<2)+0); proc(a2.y, (v2<<2)+1); proc(a2.z, (v2<<2)+2); proc(a2.w, (v2<<2)+3); }
      if (c3){ proc(a3.x, (v3<<2)+0); proc(a3.y, (v3<<2)+1); proc(a3.z, (v3<<2)+2); proc(a3.w, (v3<<2)+3); }
    }
    for (int e = (nv<<2) + gt; e < p.E; e += gs) proc(p.dst[e], e);
    // node compaction from bitmap words
    for (int w = gt; w < NW; w += gs){
      unsigned m = fits ? bmp[w] : (p.B1[w] | p.B2[w]);
      int c = __popc(m);
      if (c){
        int base = atomicAdd(&p.bar[48], c);
        int j = 0;
        while (m){
          int b = __ffs(m) - 1; m &= m - 1;
          int l = base + j; ++j;
          int v = (w << 5) | b;
          if (l < NS_MAX){ p.nodelist[l] = v; p.lidx[v] = l; }
        }
      }
    }
  }
  gbar(p.bar);

  const int ncnt = min(__hip_atomic_load(&p.bar[48], __ATOMIC_RELAXED, __HIP_MEMORY_SCOPE_AGENT), NS_MAX);
  const int ec   = min(__hip_atomic_load(&p.bar[49], __ATOMIC_RELAXED, __HIP_MEMORY_SCOPE_AGENT), ES_MAX);

  // ================= P4: localize edges + deg + zero AGG + gemm1 ==========
  for (int i = gt; i < ec; i += gs){
    int ls = p.lidx[p.esrc[i]], ld = p.lidx[p.edst[i]];
    if ((unsigned)ls < NS_MAX && (unsigned)ld < NS_MAX){
      p.els[i] = ls; p.eld[i] = ld;
      atomicAdd(&p.deg[ld], 1);
    } else { p.els[i] = -1; p.eld[i] = 0; }
  }
  for (int j = gt; j < ncnt*128; j += gs) p.AGG[j] = 0.0f;
  for (int j = gt; j < ncnt*64;  j += gs) p.AGG3[j] = 0.0f;
  for (int base = blockIdx.x*2; base < ncnt; base += NBLK*2){
    int l = base + sub; bool act = (l < ncnt);
    float xv = 0.0f;
    if (act){ int v = p.nodelist[l]; xv = p.x[(size_t)v*128 + d]; }
    row[sub][d] = xv;
    __syncthreads();
    float acc = 0.0f;
    #pragma unroll 8
    for (int k = 0; k < 128; ++k) acc = fmaf(row[sub][k], p.W1[k*128 + d], acc);
    if (act) p.H[l*128 + d] = acc;
    __syncthreads();
  }
  gbar(p.bar);

  // ================= P5: scatter layer 1 ==================================
  for (int i = blockIdx.x*2 + sub; i < ec; i += NBLK*2){
    int ls = p.els[i]; if (ls < 0) continue;
    int ld = p.eld[i];
    float w = rsqrtf((float)(p.deg[ls]+1)) * rsqrtf((float)(p.deg[ld]+1));
    atomicAdd(&p.AGG[ld*128 + d], w * p.H[ls*128 + d]);
  }
  gbar(p.bar);

  // ================= P6: ln1 (+self) + gemm2, re-zero AGG =================
  for (int base = blockIdx.x*2; base < ncnt; base += NBLK*2){
    int l = base + sub; bool act = (l < ncnt);
    float v = 0.0f;
    if (act){
      float wself = 1.0f / (float)(p.deg[l] + 1);
      v = p.AGG[l*128 + d] + p.H[l*128 + d]*wself + p.b1[d];
    }
    v = fmaxf(v, 0.0f);
    float y = ln128(v, p.g1[d], p.be1[d]);
    row[sub][d] = y;
    __syncthreads();
    float acc = 0.0f;
    #pragma unroll 8
    for (int k = 0; k < 128; ++k) acc = fmaf(row[sub][k], p.W2[k*128 + d], acc);
    if (act){ p.H[l*128 + d] = acc; p.AGG[l*128 + d] = 0.0f; }
    __syncthreads();
  }
  gbar(p.bar);

  // ================= P7: scatter layer 2 ==================================
  for (int i = blockIdx.x*2 + sub; i < ec; i += NBLK*2){
    int ls = p.els[i]; if (ls < 0) continue;
    int ld = p.eld[i];
    float w = rsqrtf((float)(p.deg[ls]+1)) * rsqrtf((float)(p.deg[ld]+1));
    atomicAdd(&p.AGG[ld*128 + d], w * p.H[ls*128 + d]);
  }
  gbar(p.bar);

  // ================= P8: ln2 + gemm3 (128 -> 64) ==========================
  for (int base = blockIdx.x*2; base < ncnt; base += NBLK*2){
    int l = base + sub; bool act = (l < ncnt);
    float v = 0.0f;
    if (act){
      float wself = 1.0f / (float)(p.deg[l] + 1);
      v = p.AGG[l*128 + d] + p.H[l*128 + d]*wself + p.b2[d];
    }
    v = fmaxf(v, 0.0f);
    float y = ln128(v, p.g2[d], p.be2[d]);
    row[sub][d] = y;
    __syncthreads();
    if (d < 64){
      float acc = 0.0f;
      #pragma unroll 8
      for (int k = 0; k < 128; ++k) acc = fmaf(row[sub][k], p.W3[k*64 + d], acc);
      if (act) p.H3[l*64 + d] = acc;
    }
    __syncthreads();
  }
  gbar(p.bar);

  // ================= P9: scatter layer 3 (dim 64) =========================
  for (int i = blockIdx.x*4 + s4; i < ec; i += NBLK*4){
    int ls = p.els[i]; if (ls < 0) continue;
    int ld = p.eld[i];
    float w = rsqrtf((float)(p.deg[ls]+1)) * rsqrtf((float)(p.deg[ld]+1));
    atomicAdd(&p.AGG3[ld*64 + t64], w * p.H3[ls*64 + t64]);
  }
  gbar(p.bar);

  // ================= P10: ln3 -> X3, last block pools =====================
  for (int base = blockIdx.x*4; base < ncnt; base += NBLK*4){
    int l = base + s4; bool act = (l < ncnt);
    float v = 0.0f;
    if (act){
      float wself = 1.0f / (float)(p.deg[l] + 1);
      v = p.AGG3[l*64 + t64] + p.H3[l*64 + t64]*wself + p.b3[t64];
    }
    v = fmaxf(v, 0.0f);
    float s = v;
    #pragma unroll
    for (int o = 32; o >= 1; o >>= 1) s += __shfl_xor(s, o);
    float mu = s * (1.0f/64.0f);
    float dv = v - mu;
    float s2 = dv*dv;
    #pragma unroll
    for (int o = 32; o >= 1; o >>= 1) s2 += __shfl_xor(s2, o);
    float var = s2 * (1.0f/64.0f);
    float y = dv * rsqrtf(var + LN_EPS) * p.g3[t64] + p.be3[t64];
    if (act) p.X3[l*64 + t64] = y;
  }
  __syncthreads();
  if (tid == 0){
    int t0 = __hip_atomic_fetch_add(&p.bar[32], 1, __ATOMIC_ACQ_REL, __HIP_MEMORY_SCOPE_AGENT);
    lastflag = (t0 == NBLK-1) ? 1 : 0;
  }
  __syncthreads();
  if (lastflag){
    __builtin_amdgcn_fence(__ATOMIC_ACQUIRE, "agent");
    float s = 0.0f;
    for (int l = s4; l < ncnt; l += 4) s += p.X3[l*64 + t64];
    redp[s4][t64] = s;
    __syncthreads();
    if (s4 == 0){
      float tot = redp[0][t64] + redp[1][t64] + redp[2][t64] + redp[3][t64];
      p.out[t64] = tot / (float)ncnt;
    }
  }
}

extern "C" void kernel_launch(void* const* d_in, const int* in_sizes, int n_in,
                              void* d_out, int out_size, void* d_ws, size_t ws_size,
                              hipStream_t stream) {
  const float* x    = (const float*)d_in[0];
  const int*   ei   = (const int*)d_in[1];
  const int*   curp = (const int*)d_in[2];

  int N = in_sizes[0] / 128;
  int E = in_sizes[1] / 2;
  int NW = (N + 31) / 32;
  int NWa = (NW + 63) & ~63;

  char* wp = (char*)d_ws;
  auto carve = [&](size_t bytes) -> void* {
    void* r = (void*)wp;
    wp += (bytes + 255) & ~(size_t)255;
    return r;
  };
  GnnParams p;
  p.x = x; p.src = ei; p.dst = ei + E; p.curp = curp;
  p.W1 = (const float*)d_in[3];  p.b1 = (const float*)d_in[4];
  p.g1 = (const float*)d_in[5];  p.be1= (const float*)d_in[6];
  p.W2 = (const float*)d_in[7];  p.b2 = (const float*)d_in[8];
  p.g2 = (const float*)d_in[9];  p.be2= (const float*)d_in[10];
  p.W3 = (const float*)d_in[11]; p.b3 = (const float*)d_in[12];
  p.g3 = (const float*)d_in[13]; p.be3= (const float*)d_in[14];

  // ---- zeroed head (one small memset) ----
  p.bar = (int*)     carve(256);
  p.B1  = (unsigned*)carve((size_t)NWa*4);
  p.B2  = (unsigned*)carve((size_t)NWa*4);
  p.deg = (int*)     carve(NS_MAX*4);
  size_t head_bytes = (size_t)(wp - (char*)d_ws);
  // ---- uninitialized tail ----
  p.nodelist = (int*)  carve(NS_MAX*4);
  p.lidx     = (int*)  carve((size_t)N*4);
  p.esrc     = (int*)  carve(ES_MAX*4);
  p.edst     = (int*)  carve(ES_MAX*4);
  p.els      = (int*)  carve(ES_MAX*4);
  p.eld      = (int*)  carve(ES_MAX*4);
  p.H        = (float*)carve((size_t)NS_MAX*128*4);
  p.AGG      = (float*)carve((size_t)NS_MAX*128*4);
  p.H3       = (float*)carve((size_t)NS_MAX*64*4);
  p.AGG3     = (float*)carve((size_t)NS_MAX*64*4);
  p.X3       = (float*)carve((size_t)NS_MAX*64*4);
  p.out      = (float*)d_out;
  p.N = N; p.E = E;
  (void)ws_size; (void)n_in; (void)out_size;

  hipMemsetAsync(d_ws, 0, head_bytes, stream);
  fused_gnn<<<dim3(NBLK), dim3(NTHR), 0, stream>>>(p);
}